// Round 7
// baseline (58.490 us; speedup 1.0000x reference)
//
#include <hip/hip_runtime.h>
#include <hip/hip_bf16.h>

typedef __bf16 bf16x8 __attribute__((ext_vector_type(8)));
typedef __bf16 bf16x4 __attribute__((ext_vector_type(4)));
typedef float  f32x4  __attribute__((ext_vector_type(4)));

#define N_BASIS   512
#define FRAME_LEN 64
#define BATCH     8
#define FRAMES    16000
#define STEP      32
#define OUT_PER_BATCH (STEP * (FRAMES - 1) + FRAME_LEN)   // 512032

#define WAVES            8
#define BLOCK            (WAVES * 64)                 // 512 threads
#define FPB              (WAVES * 16)                 // frames per tile = 128
#define TPBATCH          (FRAMES / FPB)               // 125
#define TOTAL_TILES      (BATCH * TPBATCH)            // 1000
#define TILES_PER_BLOCK  2
#define GRID             (TOTAL_TILES / TILES_PER_BLOCK)  // 500

// Barrier that orders LDS only: does NOT drain vmcnt, so global loads
// issued before it stay in flight across the barrier (the T3/T4 mechanism;
// __syncthreads would emit s_waitcnt vmcnt(0) and drain the HBM stream).
__device__ __forceinline__ void lds_barrier() {
    __builtin_amdgcn_sched_barrier(0);
    asm volatile("s_waitcnt lgkmcnt(0)" ::: "memory");
    __builtin_amdgcn_s_barrier();
    __builtin_amdgcn_sched_barrier(0);
}

// one MFMA K-step (K=32): A-frag packed from two f32x4, B from swizzled LDS
__device__ __forceinline__ void kstep(const f32x4 a0, const f32x4 a1,
                                      const __bf16* W, int kk, int lo, int hi,
                                      f32x4 acc[4]) {
    bf16x8 af;
    af[0] = (__bf16)a0[0]; af[1] = (__bf16)a0[1];
    af[2] = (__bf16)a0[2]; af[3] = (__bf16)a0[3];
    af[4] = (__bf16)a1[0]; af[5] = (__bf16)a1[1];
    af[6] = (__bf16)a1[2]; af[7] = (__bf16)a1[3];
    #pragma unroll
    for (int nt = 0; nt < 4; ++nt) {
        const int c = nt * 16 + lo;
        int e = (c << 9) + kk + hi * 8;
        e ^= (c & 7) << 3;                       // bank-conflict swizzle
        const bf16x8 b = *(const bf16x8*)(&W[e]);
        acc[nt] = __builtin_amdgcn_mfma_f32_16x16x32_bf16(af, b, acc[nt], 0, 0, 0);
    }
}

__global__ __launch_bounds__(BLOCK, 4)
void basis_ola_kernel(const float* __restrict__ weight,
                      const float* __restrict__ basis,
                      float* __restrict__ out)
{
    __shared__ __bf16 Wlds[FRAME_LEN * N_BASIS];   // 64 KiB, swizzled bf16
    __shared__ float  xbuf[2][WAVES][2][16];       // 2 KiB OLA exchange

    const int tid  = threadIdx.x;
    const int wave = tid >> 6;
    const int lane = tid & 63;
    const int lo   = lane & 15;
    const int hi   = lane >> 4;

    const int g0 = blockIdx.x * TILES_PER_BLOCK;

    // ---- stage basis f32 -> bf16 LDS (swizzle e ^= (c&7)<<3), R2 exact ----
    for (int q = tid; q < (FRAME_LEN * N_BASIS) / 4; q += BLOCK) {
        const int e = q * 4;
        const int c = e >> 9;
        const float4 v = *(const float4*)(basis + e);
        bf16x4 b;
        b[0] = (__bf16)v.x; b[1] = (__bf16)v.y;
        b[2] = (__bf16)v.z; b[3] = (__bf16)v.w;
        *(bf16x4*)(&Wlds[e ^ ((c & 7) << 3)]) = b;
    }

    // ---- carry for block's first boundary (wave 0, f32 exact), R2 exact ----
    // xbuf[1][7][nt][lo] := C[F0-1][16*(nt+2)+lo] for tile g0
    if (wave == 0) {
        const int bb0 = g0 / TPBATCH, t0 = g0 % TPBATCH;
        float val = 0.f;
        if (t0 > 0) {
            const int c  = 32 + (lane >> 1);
            const int kh = (lane & 1) * 256;
            const float* wr = weight + ((size_t)bb0 * FRAMES + (size_t)t0 * FPB - 1) * N_BASIS;
            const float* br = basis + (size_t)c * N_BASIS;
            for (int n = kh; n < kh + 256; n += 4) {
                const f32x4 a = *(const f32x4*)(wr + n);
                const f32x4 w = *(const f32x4*)(br + n);
                val += a[0]*w[0] + a[1]*w[1] + a[2]*w[2] + a[3]*w[3];
            }
        }
        val += __shfl_xor(val, 1);
        if ((lane & 1) == 0) {
            const int cc = lane >> 1;
            xbuf[1][WAVES - 1][cc >> 4][cc & 15] = val;
        }
    }

    // ---- tile-0 ks=0,1 loads: AFTER staging/carry in FIFO order (no added
    //      latency to the barrier), but issued BEFORE the non-draining
    //      barrier so they overlap it ----
    const float* arow = weight +
        ((size_t)(g0 / TPBATCH) * FRAMES + (g0 % TPBATCH) * FPB + wave * 16 + lo) * N_BASIS;
    f32x4 q0 = *(const f32x4*)(arow + hi * 8);
    f32x4 q1 = *(const f32x4*)(arow + hi * 8 + 4);
    f32x4 q2 = *(const f32x4*)(arow + 32 + hi * 8);
    f32x4 q3 = *(const f32x4*)(arow + 32 + hi * 8 + 4);

    lds_barrier();   // Wlds + pre-carry visible; HBM loads stay in flight

    for (int ti = 0; ti < TILES_PER_BLOCK; ++ti) {
        const int g    = g0 + ti;
        const int bb   = g / TPBATCH;
        const int tile = g % TPBATCH;
        const int F0   = tile * FPB;
        const int P    = ti & 1;

        f32x4 acc[4] = {};

        // ks = 0,1 from the pre-issued registers
        kstep(q0, q1, Wlds, 0,  lo, hi, acc);
        kstep(q2, q3, Wlds, 32, lo, hi, acc);

        #pragma unroll 2
        for (int ks = 2; ks < 16; ++ks) {
            const int kk = ks * 32;
            const f32x4 a0 = *(const f32x4*)(arow + kk + hi * 8);
            const f32x4 a1 = *(const f32x4*)(arow + kk + hi * 8 + 4);
            kstep(a0, a1, Wlds, kk, lo, hi, acc);
        }

        // ---- next tile's ks=0,1: issued before the epilogue barriers; the
        //      lgkm-only barriers below do NOT drain them ----
        if (ti + 1 < TILES_PER_BLOCK) {
            const int gn = g + 1;
            arow = weight +
                ((size_t)(gn / TPBATCH) * FRAMES + (gn % TPBATCH) * FPB + wave * 16 + lo) * N_BASIS;
            q0 = *(const f32x4*)(arow + hi * 8);
            q1 = *(const f32x4*)(arow + hi * 8 + 4);
            q2 = *(const f32x4*)(arow + 32 + hi * 8);
            q3 = *(const f32x4*)(arow + 32 + hi * 8 + 4);
        }

        // ---- exchange: hi==3 lanes publish trailing values ----
        if (hi == 3) {
            xbuf[P][wave][0][lo] = acc[2][3];
            xbuf[P][wave][1][lo] = acc[3][3];
        }
        lds_barrier();

        // ---- fused OLA epilogue, plain stores only ----
        float* ob = out + (size_t)bb * OUT_PER_BATCH;
        const int fbase = F0 + wave * 16 + hi * 4;

        #pragma unroll
        for (int nt = 0; nt < 2; ++nt) {
            const float up = __shfl_up(acc[nt + 2][3], 16);   // all lanes execute
            float pv;
            if (hi > 0)          pv = up;
            else if (wave > 0)   pv = xbuf[P][wave - 1][nt][lo];
            else if (tile > 0)   pv = xbuf[P ^ 1][WAVES - 1][nt][lo];
            else                 pv = 0.f;
            ob[32 * fbase + nt * 16 + lo] = acc[nt][0] + pv;

            #pragma unroll
            for (int r = 1; r < 4; ++r)
                ob[32 * (fbase + r) + nt * 16 + lo] = acc[nt][r] + acc[nt + 2][r - 1];
        }

        // last tile of a batch: trailing 32 samples have only one contributor
        if (tile == TPBATCH - 1 && wave == WAVES - 1 && hi == 3) {
            ob[32 * FRAMES + lo]      = acc[2][3];
            ob[32 * FRAMES + 16 + lo] = acc[3][3];
        }

        // boundary: tile-0 epilogue's xbuf reads must precede tile-1's
        // publish overwrite (lgkm-only; prefetched loads stay in flight)
        if (ti + 1 < TILES_PER_BLOCK) lds_barrier();
    }
}

extern "C" void kernel_launch(void* const* d_in, const int* in_sizes, int n_in,
                              void* d_out, int out_size, void* d_ws, size_t ws_size,
                              hipStream_t stream) {
    const float* weight = (const float*)d_in[0];   // (8, 16000, 512) f32
    const float* basis  = (const float*)d_in[1];   // (64, 512) f32
    float* out = (float*)d_out;                    // (8, 512032) f32

    basis_ola_kernel<<<GRID, BLOCK, 0, stream>>>(weight, basis, out);
}

// Round 8
// 55.930 us; speedup vs baseline: 1.0458x; 1.0458x over previous
//
#include <hip/hip_runtime.h>
#include <hip/hip_bf16.h>

typedef __bf16 bf16x8 __attribute__((ext_vector_type(8)));
typedef __bf16 bf16x4 __attribute__((ext_vector_type(4)));
typedef float  f32x4  __attribute__((ext_vector_type(4)));

#define N_BASIS   512
#define FRAME_LEN 64
#define BATCH     8
#define FRAMES    16000
#define STEP      32
#define OUT_PER_BATCH (STEP * (FRAMES - 1) + FRAME_LEN)   // 512032

#define WAVES            8
#define BLOCK            (WAVES * 64)                 // 512 threads
#define FPB              (WAVES * 16)                 // frames per tile = 128
#define TPBATCH          (FRAMES / FPB)               // 125
#define TOTAL_TILES      (BATCH * TPBATCH)            // 1000
#define TILES_PER_BLOCK  4                            // R8: 2 -> 4 (only change vs R2)
#define GRID             (TOTAL_TILES / TILES_PER_BLOCK)  // 250 = one block per CU

// C[f][c] = sum_n weight[f][n] * W[c][n]; out[b][32f + c] = C[f][c] + C[f-1][c+32].
// Every output sample is written by exactly ONE plain store:
//   - thread-local merge for r>=1 (partner acc[nt+2][r-1] in same thread)
//   - __shfl_up(16) for r==0, hi>=1 (partner in lane-16)
//   - LDS exchange xbuf for r==0, hi==0 (previous wave / previous tile, parity chain)
//   - VALU-computed carry row for the block's first tile boundary
// Blocks may span batch boundaries: per-tile bb/tile handle carry=0 at batch
// start (tile==0) and the trailing 32-sample store at batch end.
__global__ __launch_bounds__(BLOCK, 4)
void basis_ola_kernel(const float* __restrict__ weight,
                      const float* __restrict__ basis,
                      float* __restrict__ out)
{
    // basis as bf16, XOR-swizzled (row stride 1KB would be fully bank-conflicted)
    __shared__ __bf16 Wlds[FRAME_LEN * N_BASIS];      // 64 KiB
    __shared__ float xbuf[2][WAVES][2][16];           // 2 KiB, tile-parity dbuf

    const int tid = threadIdx.x;

    // ---- stage basis (64x512 f32 -> bf16 LDS), elem swizzle e ^= (c&7)<<3 ----
    for (int q = tid; q < (FRAME_LEN * N_BASIS) / 4; q += BLOCK) {
        const int e = q * 4;
        const int c = e >> 9;
        const float4 v = *(const float4*)(basis + e);
        bf16x4 b;
        b[0] = (__bf16)v.x; b[1] = (__bf16)v.y;
        b[2] = (__bf16)v.z; b[3] = (__bf16)v.w;
        *(bf16x4*)(&Wlds[e ^ ((c & 7) << 3)]) = b;
    }

    const int wave = tid >> 6;
    const int lane = tid & 63;
    const int lo   = lane & 15;
    const int hi   = lane >> 4;

    const int g0 = blockIdx.x * TILES_PER_BLOCK;

    // ---- carry for the block's FIRST tile boundary ----
    // xbuf[1][7][nt][lo] := C[F0-1][16*(nt+2)+lo] for tile g0
    // (zero if g0 is the first tile of a batch)
    if (wave == 0) {
        const int bb0 = g0 / TPBATCH, t0 = g0 % TPBATCH;
        float val = 0.f;
        if (t0 > 0) {
            const int c  = 32 + (lane >> 1);          // basis row 32..63
            const int kh = (lane & 1) * 256;          // half of K per lane
            const float* wr = weight + ((size_t)bb0 * FRAMES + (size_t)t0 * FPB - 1) * N_BASIS;
            const float* br = basis + (size_t)c * N_BASIS;
            for (int n = kh; n < kh + 256; n += 4) {
                const f32x4 a = *(const f32x4*)(wr + n);
                const f32x4 w = *(const f32x4*)(br + n);
                val += a[0]*w[0] + a[1]*w[1] + a[2]*w[2] + a[3]*w[3];
            }
        }
        val += __shfl_xor(val, 1);
        if ((lane & 1) == 0) {
            const int cc = lane >> 1;                 // 0..31  (c-32)
            xbuf[1][WAVES - 1][cc >> 4][cc & 15] = val;
        }
    }
    __syncthreads();

    for (int ti = 0; ti < TILES_PER_BLOCK; ++ti) {
        const int g    = g0 + ti;
        const int bb   = g / TPBATCH;
        const int tile = g % TPBATCH;
        const int F0   = tile * FPB;
        const int P    = ti & 1;

        // A-fragment row (mfma_f32_16x16x32_bf16: row = lane&15, k = (lane>>4)*8 + j)
        const float* arow = weight +
            ((size_t)bb * FRAMES + F0 + wave * 16 + lo) * (size_t)N_BASIS;

        f32x4 acc[4] = {};   // nt -> columns nt*16 + lo

        #pragma unroll 2
        for (int ks = 0; ks < N_BASIS / 32; ++ks) {
            const int kk = ks * 32;
            const float4 a0 = *(const float4*)(arow + kk + hi * 8);
            const float4 a1 = *(const float4*)(arow + kk + hi * 8 + 4);
            bf16x8 af;
            af[0] = (__bf16)a0.x; af[1] = (__bf16)a0.y;
            af[2] = (__bf16)a0.z; af[3] = (__bf16)a0.w;
            af[4] = (__bf16)a1.x; af[5] = (__bf16)a1.y;
            af[6] = (__bf16)a1.z; af[7] = (__bf16)a1.w;

            #pragma unroll
            for (int nt = 0; nt < 4; ++nt) {
                const int c = nt * 16 + lo;
                int e = (c << 9) + kk + hi * 8;
                e ^= (c & 7) << 3;
                const bf16x8 bfr = *(const bf16x8*)(&Wlds[e]);
                acc[nt] = __builtin_amdgcn_mfma_f32_16x16x32_bf16(af, bfr, acc[nt], 0, 0, 0);
            }
        }

        // ---- exchange: hi==3 lanes publish trailing values ----
        // acc[nt+2][3] = C[F0+16w+15][16*(nt+2)+lo]
        if (hi == 3) {
            xbuf[P][wave][0][lo] = acc[2][3];
            xbuf[P][wave][1][lo] = acc[3][3];
        }
        __syncthreads();

        // ---- fused OLA epilogue, plain stores only ----
        float* ob = out + (size_t)bb * OUT_PER_BATCH;
        const int fbase = F0 + wave * 16 + hi * 4;

        #pragma unroll
        for (int nt = 0; nt < 2; ++nt) {
            // r == 0: partner C[fbase-1][16*(nt+2)+lo]
            const float up = __shfl_up(acc[nt + 2][3], 16);   // all lanes execute
            float pv;
            if (hi > 0)          pv = up;
            else if (wave > 0)   pv = xbuf[P][wave - 1][nt][lo];
            else if (tile > 0)   pv = xbuf[P ^ 1][WAVES - 1][nt][lo];
            else                 pv = 0.f;
            ob[32 * fbase + nt * 16 + lo] = acc[nt][0] + pv;

            #pragma unroll
            for (int r = 1; r < 4; ++r) {
                ob[32 * (fbase + r) + nt * 16 + lo] = acc[nt][r] + acc[nt + 2][r - 1];
            }
        }

        // last tile of a batch: trailing 32 samples get only C[15999][c+32]
        if (tile == TPBATCH - 1 && wave == WAVES - 1 && hi == 3) {
            ob[32 * FRAMES + 0 * 16 + lo] = acc[2][3];
            ob[32 * FRAMES + 1 * 16 + lo] = acc[3][3];
        }

        __syncthreads();   // protect xbuf reads from next tile's writes
    }
}

extern "C" void kernel_launch(void* const* d_in, const int* in_sizes, int n_in,
                              void* d_out, int out_size, void* d_ws, size_t ws_size,
                              hipStream_t stream) {
    const float* weight = (const float*)d_in[0];   // (8, 16000, 512) f32
    const float* basis  = (const float*)d_in[1];   // (64, 512) f32
    float* out = (float*)d_out;                    // (8, 512032) f32

    basis_ola_kernel<<<GRID, BLOCK, 0, stream>>>(weight, basis, out);
}